// Round 1
// baseline (1760.023 us; speedup 1.0000x reference)
//
#include <hip/hip_runtime.h>
#include <cstdint>

typedef __bf16 bf16_t;
typedef bf16_t bf16x8 __attribute__((ext_vector_type(8)));
typedef float f32x4v __attribute__((ext_vector_type(4)));
typedef float f32x16 __attribute__((ext_vector_type(16)));
typedef unsigned long long u64;

#define GLD16(gp, lp)                                                        \
  __builtin_amdgcn_global_load_lds(                                          \
      (const __attribute__((address_space(1))) unsigned int*)(gp),           \
      (__attribute__((address_space(3))) unsigned int*)(lp), 16, 0, 0)

struct GDesc {
  const void* A; const void* Bt; const void* bias;
  bf16_t* outN; bf16_t* outT;
  int M, N, K, lda, ldbt, ldN, ldT, bstart, nbm, aext, bext;
};
struct GBatch { const unsigned* flagp; int nd; GDesc d[6]; };

__device__ __forceinline__ int imin(int a, int b) { return a < b ? a : b; }

// flag: 1 = inputs are bf16, 0 = inputs are f32.
__global__ __launch_bounds__(256) void detect_dtype(const void* probe, unsigned* flag) {
  __shared__ int cnt;
  if (threadIdx.x == 0) cnt = 0;
  __syncthreads();
  const unsigned short* u = (const unsigned short*)probe;
  int c = 0;
  for (int i = threadIdx.x; i < 4096; i += 256) {
    int e = (u[2 * i] >> 7) & 0xFF;
    if (e >= 97 && e <= 157) c++;   // |x| roughly in [2^-30, 2^30]
  }
  atomicAdd(&cnt, c);
  __syncthreads();
  if (threadIdx.x == 0) *flag = (cnt >= 3277) ? 1u : 0u;  // 80% of 4096
}

// C = A[M,K] * B[K,N], A row-major, B given transposed (Bt[N,K] row-major).
// Block tile 128x128, 4 waves (2x2), per-wave 64x64 via 2x2 MFMA 32x32x16 bf16.
// K-loop: double-buffered LDS, 2-phase software pipeline (1-deep prefetch),
// one raw s_barrier + explicit s_waitcnt per K-step so the global loads for
// tile k+1 stay in flight under tile k's ds_read+MFMA phase.
__global__ __launch_bounds__(256) void gemm_stage(GBatch gb) {
  __shared__ bf16_t sA[2][128 * 32];
  __shared__ bf16_t sB[2][128 * 32];
  __shared__ float sT[32 * 132];

  const int bid = blockIdx.x;
  int di = 0;
#pragma unroll 1
  for (int i = 1; i < gb.nd; ++i)
    if (bid >= gb.d[i].bstart) di = i;
  const GDesc g = gb.d[di];

  const unsigned fl = *gb.flagp;
  const bool a32 = g.aext && (fl == 0);
  const bool b32 = g.bext && (fl == 0);
  const bool anyf = a32 || b32;

  const int t = threadIdx.x;
  const int w = t >> 6, lane = t & 63;
  const int local = bid - g.bstart;
  const int bm = local % g.nbm, bn = local / g.nbm;
  const int m0 = bm * 128, c0 = bn * 128;

  // staging: thread t stages 8 bf16 (16B) at LDS element t*8 = row (t>>2), col (t&3)*8
  const int srow = t >> 2;
  const int sc = (t & 3) * 8;
  const u64 eA0 = (u64)imin(m0 + srow, g.M - 1) * g.lda + sc;
  const u64 eA1 = (u64)imin(m0 + 64 + srow, g.M - 1) * g.lda + sc;
  const u64 eB0 = (u64)imin(c0 + srow, g.N - 1) * g.ldbt + sc;
  const u64 eB1 = (u64)imin(c0 + 64 + srow, g.N - 1) * g.ldbt + sc;

  const bf16_t* Ab = (const bf16_t*)g.A;
  const float*  Af = (const float*)g.A;
  const bf16_t* Bb = (const bf16_t*)g.Bt;
  const float*  Bf = (const float*)g.Bt;

  const int wm = w & 1, wn = w >> 1;
  const int lrow = lane & 31, lhalf = lane >> 5;
  const int aoff = (wm * 64 + lrow) * 32 + lhalf * 8;
  const int boff = (wn * 64 + lrow) * 32 + lhalf * 8;

  f32x16 acc[2][2] = {};

  auto cvt2 = [](float4 u0, float4 u1) {
    bf16x8 r;
    r[0] = (bf16_t)u0.x; r[1] = (bf16_t)u0.y; r[2] = (bf16_t)u0.z; r[3] = (bf16_t)u0.w;
    r[4] = (bf16_t)u1.x; r[5] = (bf16_t)u1.y; r[6] = (bf16_t)u1.z; r[7] = (bf16_t)u1.w;
    return r;
  };
  auto cvt8 = [](const float* p) {
    float4 u0 = *(const float4*)p, u1 = *(const float4*)(p + 4);
    bf16x8 r;
    r[0] = (bf16_t)u0.x; r[1] = (bf16_t)u0.y; r[2] = (bf16_t)u0.z; r[3] = (bf16_t)u0.w;
    r[4] = (bf16_t)u1.x; r[5] = (bf16_t)u1.y; r[6] = (bf16_t)u1.z; r[7] = (bf16_t)u1.w;
    return r;
  };

  // f32-path register staging (statically indexed — stays in VGPRs)
  float4 ra0, ra1, ra2, ra3, rb0, rb1, rb2, rb3;

  auto issue_tile = [&](int kk, int buf) {
    const u64 kb = (u64)kk * 32;
    bf16_t* dA = &sA[buf][0];
    bf16_t* dB = &sB[buf][0];
    if (!a32) {
      GLD16(Ab + eA0 + kb, dA + w * 512);
      GLD16(Ab + eA1 + kb, dA + w * 512 + 2048);
    } else {
      const float* p0 = Af + eA0 + kb;
      const float* p1 = Af + eA1 + kb;
      ra0 = *(const float4*)p0; ra1 = *(const float4*)(p0 + 4);
      ra2 = *(const float4*)p1; ra3 = *(const float4*)(p1 + 4);
    }
    if (!b32) {
      GLD16(Bb + eB0 + kb, dB + w * 512);
      GLD16(Bb + eB1 + kb, dB + w * 512 + 2048);
    } else {
      const float* p0 = Bf + eB0 + kb;
      const float* p1 = Bf + eB1 + kb;
      rb0 = *(const float4*)p0; rb1 = *(const float4*)(p0 + 4);
      rb2 = *(const float4*)p1; rb3 = *(const float4*)(p1 + 4);
    }
  };

  auto write_tile = [&](int buf) {  // f32 path: cvt regs -> LDS (after vmcnt wait)
    if (a32) {
      *(bf16x8*)&sA[buf][(u64)t * 8] = cvt2(ra0, ra1);
      *(bf16x8*)&sA[buf][(u64)t * 8 + 2048] = cvt2(ra2, ra3);
    }
    if (b32) {
      *(bf16x8*)&sB[buf][(u64)t * 8] = cvt2(rb0, rb1);
      *(bf16x8*)&sB[buf][(u64)t * 8 + 2048] = cvt2(rb2, rb3);
    }
  };

  auto mfma_step = [&](const bf16_t* bA, const bf16_t* bB) {
    bf16x8 af[2][2], bb[2][2];
#pragma unroll
    for (int s = 0; s < 2; ++s)
#pragma unroll
      for (int h = 0; h < 2; ++h) {
        af[s][h] = *(const bf16x8*)&bA[aoff + s * 1024 + h * 16];
        bb[s][h] = *(const bf16x8*)&bB[boff + s * 1024 + h * 16];
      }
#pragma unroll
    for (int h = 0; h < 2; ++h)
#pragma unroll
      for (int sm = 0; sm < 2; ++sm)
#pragma unroll
        for (int sn = 0; sn < 2; ++sn)
          acc[sm][sn] = __builtin_amdgcn_mfma_f32_32x32x16_bf16(
              af[sm][h], bb[sn][h], acc[sm][sn], 0, 0, 0);
  };

  const int kfull = g.K >> 5;

  // ---- prologue: tile 0 -> buf 0
  issue_tile(0, 0);
  if (anyf) {
    asm volatile("s_waitcnt vmcnt(0)" ::: "memory");
    write_tile(0);
  }
  asm volatile("s_waitcnt vmcnt(0) lgkmcnt(0)" ::: "memory");
  __builtin_amdgcn_s_barrier();

  // ---- pipelined main loop: one barrier per K-step, loads overlap MFMA
#pragma unroll 1
  for (int kk = 0; kk < kfull; ++kk) {
    const int cur = kk & 1;
    if (kk + 1 < kfull) {
      issue_tile(kk + 1, cur ^ 1);                 // async: next tile in flight
      mfma_step(&sA[cur][0], &sB[cur][0]);         // compute current tile
      if (anyf) {
        asm volatile("s_waitcnt vmcnt(0)" ::: "memory");
        write_tile(cur ^ 1);                       // cvt+ds_write next tile
      }
    } else {
      mfma_step(&sA[cur][0], &sB[cur][0]);
    }
    asm volatile("s_waitcnt vmcnt(0) lgkmcnt(0)" ::: "memory");
    __builtin_amdgcn_s_barrier();
  }

  if (g.K & 16) {  // K tail of 16 (K = 2000, 6000): stage 16 cols, zero the rest
    const u64 k0 = (u64)(g.K & ~31);
    const int row = t >> 1, c8 = (t & 1) * 8;
    const u64 ea = (u64)imin(m0 + row, g.M - 1) * g.lda + k0 + c8;
    const u64 eb = (u64)imin(c0 + row, g.N - 1) * g.ldbt + k0 + c8;
    bf16x8 va, vb;
    if (!a32) va = *(const bf16x8*)(Ab + ea);
    else va = cvt8(Af + ea);
    if (!b32) vb = *(const bf16x8*)(Bb + eb);
    else vb = cvt8(Bf + eb);
    uint4 z = {0, 0, 0, 0};
    *(bf16x8*)&sA[0][row * 32 + c8] = va;
    *(uint4*)&sA[0][row * 32 + 16 + c8] = z;
    *(bf16x8*)&sB[0][row * 32 + c8] = vb;
    *(uint4*)&sB[0][row * 32 + 16 + c8] = z;
    __syncthreads();
    mfma_step(&sA[0][0], &sB[0][0]);
    __syncthreads();
  }

  // C/D layout (m74/m101): col = lane&31, row = (reg&3) + 8*(reg>>2) + 4*(lane>>5)
  if (g.bias) {  // bias arrays are always external
#pragma unroll
    for (int sm = 0; sm < 2; ++sm)
#pragma unroll
      for (int reg = 0; reg < 16; ++reg) {
        int mg = imin(m0 + wm * 64 + sm * 32 + (reg & 3) + 8 * (reg >> 2) + 4 * lhalf,
                      g.M - 1);
        float bv = (fl == 0) ? ((const float*)g.bias)[mg]
                             : (float)((const bf16_t*)g.bias)[mg];
        acc[sm][0][reg] += bv;
        acc[sm][1][reg] += bv;
      }
  }
  if (g.outN) {
#pragma unroll
    for (int sm = 0; sm < 2; ++sm)
#pragma unroll
      for (int sn = 0; sn < 2; ++sn) {
        int cg = c0 + wn * 64 + sn * 32 + lrow;
        if (cg < g.N) {
#pragma unroll
          for (int reg = 0; reg < 16; ++reg) {
            int mg = m0 + wm * 64 + sm * 32 + (reg & 3) + 8 * (reg >> 2) + 4 * lhalf;
            if (mg < g.M) g.outN[(u64)mg * g.ldN + cg] = (bf16_t)acc[sm][sn][reg];
          }
        }
      }
  }
  if (g.outT) {  // transpose 32-col chunks through LDS, coalesced bf16x4 stores
#pragma unroll
    for (int cc = 0; cc < 4; ++cc) {
      __syncthreads();
      if (wn == (cc >> 1)) {
        const int sn = cc & 1;
#pragma unroll
        for (int sm = 0; sm < 2; ++sm)
#pragma unroll
          for (int rq = 0; rq < 4; ++rq) {
            f32x4v v;
            v.x = acc[sm][sn][rq * 4 + 0];
            v.y = acc[sm][sn][rq * 4 + 1];
            v.z = acc[sm][sn][rq * 4 + 2];
            v.w = acc[sm][sn][rq * 4 + 3];
            int ml = wm * 64 + sm * 32 + 8 * rq + 4 * lhalf;
            *(f32x4v*)&sT[lrow * 132 + ml] = v;
          }
      }
      __syncthreads();
#pragma unroll
      for (int p = 0; p < 4; ++p) {
        int c = (t >> 5) + p * 8, mq = t & 31;
        f32x4v v = *(const f32x4v*)&sT[c * 132 + mq * 4];
        int cg = c0 + cc * 32 + c;
        if (cg < g.N) {
          union { bf16_t b[4]; uint2 u; } cv;
          cv.b[0] = (bf16_t)v.x; cv.b[1] = (bf16_t)v.y;
          cv.b[2] = (bf16_t)v.z; cv.b[3] = (bf16_t)v.w;
          *(uint2*)(g.outT + (u64)cg * g.ldT + m0 + mq * 4) = cv.u;
        }
      }
    }
  }
}

// out[j][i] = (bf16)in[i][j]; 64x64 tiles; dual-dtype input read.
__global__ __launch_bounds__(256) void transpose_any(const void* in, bf16_t* out,
                                                     int Ri, int Ci, int tilesC,
                                                     const unsigned* flagp) {
  __shared__ bf16_t tile[64 * 65];
  const bool f32m = (*flagp == 0);
  const int bi = blockIdx.x / tilesC, bj = blockIdx.x % tilesC;
  const int i0 = bi * 64, j0 = bj * 64;
  const int t = threadIdx.x;
#pragma unroll
  for (int it = 0; it < 16; ++it) {
    int flidx = t + it * 256;
    int r = flidx >> 6, c = flidx & 63;
    int gi = i0 + r, gj = j0 + c;
    bf16_t v = (bf16_t)0.f;
    if (gi < Ri && gj < Ci) {
      u64 idx = (u64)gi * Ci + gj;
      v = f32m ? (bf16_t)((const float*)in)[idx] : ((const bf16_t*)in)[idx];
    }
    tile[r * 65 + c] = v;
  }
  __syncthreads();
#pragma unroll
  for (int it = 0; it < 2; ++it) {
    int flidx = t + it * 256;
    int c = flidx >> 3, rb = (flidx & 7) * 8;
    int gj = j0 + c;
    if (gj < Ci && (i0 + rb) < Ri) {
      union { bf16_t b[8]; uint4 u; } cv;
#pragma unroll
      for (int k2 = 0; k2 < 8; ++k2) cv.b[k2] = tile[(rb + k2) * 65 + c];
      *(uint4*)(out + (u64)gj * Ri + i0 + rb) = cv.u;
    }
  }
}

// Wp[o][k*128+i] = w[i][o][k]  (w: [128,128,ks] row-major), dual-dtype read
struct RPack {
  const void* src[3]; bf16_t* dst[3];
  int R[3], ks[3], base[3], total;
  const unsigned* flagp;
};
__global__ __launch_bounds__(256) void repack_w(RPack rp) {
  int id = blockIdx.x * 256 + threadIdx.x;
  if (id >= rp.total) return;
  const bool f32m = (*rp.flagp == 0);
  int si = 0;
  if (id >= rp.base[1]) si = 1;
  if (id >= rp.base[2]) si = 2;
  int e = id - rp.base[si];
  int R = rp.R[si], ks = rp.ks[si];
  int o = e / R, col = e - o * R;
  int k = col >> 7, i = col & 127;
  u64 sidx = ((u64)i * 128 + o) * ks + k;
  rp.dst[si][e] = f32m ? (bf16_t)((const float*)rp.src[si])[sidx]
                       : ((const bf16_t*)rp.src[si])[sidx];
}

__global__ __launch_bounds__(256) void final_head(const bf16_t* h0t, const void* ow,
                                                  const void* ob, void* out,
                                                  const unsigned* flagp) {
  int n = blockIdx.x * 256 + threadIdx.x;
  if (n >= 2000) return;
  const bool f32m = (*flagp == 0);
  float a0 = f32m ? ((const float*)ob)[0] : (float)((const bf16_t*)ob)[0];
  float a1 = f32m ? ((const float*)ob)[1] : (float)((const bf16_t*)ob)[1];
#pragma unroll 4
  for (int i = 0; i < 128; ++i) {
    float hv = (float)h0t[i * 2048 + n];
    float w0 = f32m ? ((const float*)ow)[i] : (float)((const bf16_t*)ow)[i];
    float w1 = f32m ? ((const float*)ow)[128 + i] : (float)((const bf16_t*)ow)[128 + i];
    a0 += hv * w0;
    a1 += hv * w1;
  }
  float s0 = 1.f / (1.f + __expf(-a0));
  float s1 = 1.f / (1.f + __expf(-a1));
  if (f32m) {
    ((float*)out)[n * 2 + 0] = s0;
    ((float*)out)[n * 2 + 1] = s1;
  } else {
    ((bf16_t*)out)[n * 2 + 0] = (bf16_t)s0;
    ((bf16_t*)out)[n * 2 + 1] = (bf16_t)s1;
  }
}

extern "C" void kernel_launch(void* const* d_in, const int* in_sizes, int n_in,
                              void* d_out, int out_size, void* d_ws, size_t ws_size,
                              hipStream_t stream) {
  const void *x0 = d_in[0], *x1 = d_in[1], *x2 = d_in[2];
  const void *L0 = d_in[3], *L1d = d_in[4], *L1u = d_in[5];
  const void *B1m = d_in[8];
  const void *B2m = d_in[9];
  const void *inw0 = d_in[10], *inb0 = d_in[11], *inw1 = d_in[12], *inb1 = d_in[13],
             *inw2 = d_in[14], *inb2 = d_in[15];
  const void *w0a = d_in[16], *w1a = d_in[17], *w0b = d_in[19];
  const void *outw = d_in[22], *outb = d_in[23];
  // dead inputs: L2d(6), L2u(7), l0_w2(18), l1_w1(20), l1_w2(21) — face space
  // never reaches the node logits.

  char* wsb = (char*)d_ws;
  size_t off = 0;
  auto alloc = [&](size_t elems) {
    bf16_t* p = (bf16_t*)(wsb + off);
    off = (off + elems * 2 + 255) & ~(size_t)255;
    return p;
  };
  unsigned* flagp = (unsigned*)alloc(128);
  bf16_t* B1t = alloc((size_t)6000 * 2000);   // B1^T
  bf16_t* h0t = alloc(128 * 2048);            // channel-major features [128, n_pad]
  bf16_t* h1t = alloc(128 * 6016);
  bf16_t* h2t = alloc(128 * 4096);
  bf16_t* p_t = alloc(128 * 2048);
  bf16_t* q_t = alloc(128 * 6016);
  bf16_t* r_t = alloc(128 * 6016);
  bf16_t* a_t = alloc(128 * 2048);
  bf16_t* c_t = alloc(128 * 2048);
  bf16_t* e_t = alloc(128 * 6016);
  bf16_t* g_t = alloc(128 * 6016);
  bf16_t* j_t = alloc(128 * 6016);
  bf16_t* l_t = alloc(128 * 6016);
  bf16_t* sA0 = alloc((size_t)2000 * 768);    // layer-1 x0 slice stack [n, 6*128]
  bf16_t* sA1 = alloc((size_t)6000 * 1408);   // layer-1 x1 slice stack [n, 11*128]
  bf16_t* sB0 = alloc((size_t)2000 * 768);    // layer-2 x0 slice stack
  bf16_t* Wp0a = alloc(768 * 128);
  bf16_t* Wp1a = alloc(1408 * 128);
  bf16_t* Wp0b = alloc(768 * 128);

  // 0) dtype probe (on L0)
  detect_dtype<<<1, 256, 0, stream>>>(L0, flagp);

  // 1) repack einsum weights (only the alive ones)
  RPack rp{};
  rp.src[0] = w0a; rp.dst[0] = Wp0a; rp.R[0] = 768;  rp.ks[0] = 6;  rp.base[0] = 0;
  rp.src[1] = w1a; rp.dst[1] = Wp1a; rp.R[1] = 1408; rp.ks[1] = 11; rp.base[1] = 98304;
  rp.src[2] = w0b; rp.dst[2] = Wp0b; rp.R[2] = 768;  rp.ks[2] = 6;  rp.base[2] = 98304 + 180224;
  rp.total = 98304 + 180224 + 98304;
  rp.flagp = flagp;
  repack_w<<<(rp.total + 255) / 256, 256, 0, stream>>>(rp);

  // 2) B1^T
  transpose_any<<<32 * 94, 256, 0, stream>>>(B1m, B1t, 2000, 6000, 94, flagp);

  GBatch gb; int tot;
  gb.flagp = flagp;
  auto reset = [&] { gb.nd = 0; tot = 0; };
  auto add = [&](const void* A, int aext, const void* Bt, int bext, const void* bias,
                 bf16_t* outN, int ldN, bf16_t* outT, int ldT,
                 int M, int N, int K, int lda, int ldbt) {
    GDesc& d = gb.d[gb.nd++];
    d.A = A; d.Bt = Bt; d.bias = bias; d.outN = outN; d.outT = outT;
    d.M = M; d.N = N; d.K = K; d.lda = lda; d.ldbt = ldbt; d.ldN = ldN; d.ldT = ldT;
    d.aext = aext; d.bext = bext;
    d.bstart = tot; d.nbm = (M + 127) >> 7;
    tot += d.nbm * ((N + 127) >> 7);
  };
  auto fire = [&] { gemm_stage<<<tot, 256, 0, stream>>>(gb); };

  // input linears: h^T = W x^T (+b). M=128(ch), N=n, K=128.
  reset();
  add(inw0, 1, x0, 1, inb0, h0t, 2048, sA0, 768, 128, 2000, 128, 128, 128);
  add(inw1, 1, x1, 1, inb1, h1t, 6016, sA1, 1408, 128, 6000, 128, 128, 128);
  add(inw2, 1, x2, 1, inb2, h2t, 4096, nullptr, 0, 128, 4000, 128, 128, 128);
  fire();

  // layer 1, stage A: projections + first cheb steps on h
  reset();
  add(B1m, 1, h1t, 0, nullptr, sA0 + 3 * 128, 768, p_t, 2048, 2000, 128, 6000, 6000, 6016);  // p
  add(B1t, 0, h0t, 0, nullptr, sA1 + 5 * 128, 1408, q_t, 6016, 6000, 128, 2000, 2000, 2048); // q
  add(B2m, 1, h2t, 0, nullptr, sA1 + 8 * 128, 1408, r_t, 6016, 6000, 128, 4000, 4000, 4096); // r
  add(L0, 1, h0t, 0, nullptr, sA0 + 1 * 128, 768, a_t, 2048, 2000, 128, 2000, 2000, 2048);   // a
  add(L1d, 1, h1t, 0, nullptr, sA1 + 1 * 128, 1408, e_t, 6016, 6000, 128, 6000, 6000, 6016); // e
  add(L1u, 1, h1t, 0, nullptr, sA1 + 3 * 128, 1408, g_t, 6016, 6000, 128, 6000, 6000, 6016); // g
  fire();

  // layer 1, stage B
  reset();
  add(L0, 1, p_t, 0, nullptr, sA0 + 4 * 128, 768, c_t, 2048, 2000, 128, 2000, 2000, 2048);   // c
  add(L0, 1, a_t, 0, nullptr, sA0 + 2 * 128, 768, nullptr, 0, 2000, 128, 2000, 2000, 2048);  // b
  add(L1d, 1, q_t, 0, nullptr, sA1 + 6 * 128, 1408, j_t, 6016, 6000, 128, 6000, 6000, 6016); // j
  add(L1d, 1, e_t, 0, nullptr, sA1 + 2 * 128, 1408, nullptr, 0, 6000, 128, 6000, 6000, 6016);// f
  add(L1u, 1, r_t, 0, nullptr, sA1 + 9 * 128, 1408, l_t, 6016, 6000, 128, 6000, 6000, 6016); // l
  add(L1u, 1, g_t, 0, nullptr, sA1 + 4 * 128, 1408, nullptr, 0, 6000, 128, 6000, 6000, 6016);// i
  fire();

  // layer 1, stage C
  reset();
  add(L0, 1, c_t, 0, nullptr, sA0 + 5 * 128, 768, nullptr, 0, 2000, 128, 2000, 2000, 2048);  // d
  add(L1d, 1, j_t, 0, nullptr, sA1 + 7 * 128, 1408, nullptr, 0, 6000, 128, 6000, 6000, 6016);// k
  add(L1u, 1, l_t, 0, nullptr, sA1 + 10 * 128, 1408, nullptr, 0, 6000, 128, 6000, 6000, 6016);// m
  fire();

  // layer 1, stage D: einsums (y2 dead)
  reset();
  add(sA0, 0, Wp0a, 0, nullptr, sB0, 768, h0t, 2048, 2000, 128, 768, 768, 768);     // y0 -> h0'
  add(sA1, 0, Wp1a, 0, nullptr, nullptr, 0, h1t, 6016, 6000, 128, 1408, 1408, 1408);// y1 -> h1'
  fire();

  // layer 2 (only the node-space path survives)
  reset();
  add(B1m, 1, h1t, 0, nullptr, sB0 + 3 * 128, 768, p_t, 2048, 2000, 128, 6000, 6000, 6016);  // p2
  add(L0, 1, h0t, 0, nullptr, sB0 + 1 * 128, 768, a_t, 2048, 2000, 128, 2000, 2000, 2048);   // a2
  fire();
  reset();
  add(L0, 1, p_t, 0, nullptr, sB0 + 4 * 128, 768, c_t, 2048, 2000, 128, 2000, 2000, 2048);   // c2
  add(L0, 1, a_t, 0, nullptr, sB0 + 2 * 128, 768, nullptr, 0, 2000, 128, 2000, 2000, 2048);  // b2
  fire();
  reset();
  add(L0, 1, c_t, 0, nullptr, sB0 + 5 * 128, 768, nullptr, 0, 2000, 128, 2000, 2000, 2048);  // d2
  fire();
  reset();
  add(sB0, 0, Wp0b, 0, nullptr, nullptr, 0, h0t, 2048, 2000, 128, 768, 768, 768);            // y0' -> h0''
  fire();

  // head: logits + sigmoid
  final_head<<<8, 256, 0, stream>>>(h0t, outw, outb, d_out, flagp);
}

// Round 2
// 1049.923 us; speedup vs baseline: 1.6763x; 1.6763x over previous
//
#include <hip/hip_runtime.h>
#include <cstdint>

typedef __bf16 bf16_t;
typedef bf16_t bf16x8 __attribute__((ext_vector_type(8)));
typedef float f32x4v __attribute__((ext_vector_type(4)));
typedef float f32x16 __attribute__((ext_vector_type(16)));
typedef unsigned long long u64;

#define GLD16(gp, lp)                                                        \
  __builtin_amdgcn_global_load_lds(                                          \
      (const __attribute__((address_space(1))) unsigned int*)(gp),           \
      (__attribute__((address_space(3))) unsigned int*)(lp), 16, 0, 0)

struct GDesc {
  const void* A; const void* Ac; const void* Bt; const void* Bc; const void* bias;
  bf16_t* outN; bf16_t* outT;
  int M, N, K, lda, ldbt, ldN, ldT, bstart, nbm, aext, bext;
};
struct GBatch { const unsigned* flagp; int nd; GDesc d[6]; };

__device__ __forceinline__ int imin(int a, int b) { return a < b ? a : b; }

// flag: 1 = inputs are bf16, 0 = inputs are f32.
__global__ __launch_bounds__(256) void detect_dtype(const void* probe, unsigned* flag) {
  __shared__ int cnt;
  if (threadIdx.x == 0) cnt = 0;
  __syncthreads();
  const unsigned short* u = (const unsigned short*)probe;
  int c = 0;
  for (int i = threadIdx.x; i < 4096; i += 256) {
    int e = (u[2 * i] >> 7) & 0xFF;
    if (e >= 97 && e <= 157) c++;   // |x| roughly in [2^-30, 2^30]
  }
  atomicAdd(&cnt, c);
  __syncthreads();
  if (threadIdx.x == 0) *flag = (cnt >= 3277) ? 1u : 0u;  // 80% of 4096
}

// Streaming f32 -> bf16 conversion for external operands (runs only when f32).
struct CvtJob { const float* src; bf16_t* dst; };
struct CvtBatch {
  const unsigned* flagp; int nj; unsigned total4;
  unsigned base[12]; CvtJob j[12];
};
__global__ __launch_bounds__(256) void cvt_f32_bf16(CvtBatch cb) {
  if (*cb.flagp != 0) return;  // already bf16 — conv buffers unused
  const unsigned stride = gridDim.x * 256;
  for (unsigned idx = blockIdx.x * 256 + threadIdx.x; idx < cb.total4; idx += stride) {
    int ji = 0;
#pragma unroll 1
    for (int i = 1; i < cb.nj; ++i)
      if (idx >= cb.base[i]) ji = i;
    const unsigned e = idx - cb.base[ji];
    float4 v = ((const float4*)cb.j[ji].src)[e];
    union { bf16_t b[4]; uint2 u; } o;
    o.b[0] = (bf16_t)v.x; o.b[1] = (bf16_t)v.y;
    o.b[2] = (bf16_t)v.z; o.b[3] = (bf16_t)v.w;
    *(uint2*)(cb.j[ji].dst + (u64)e * 4) = o.u;
  }
}

// C = A[M,K] * B[K,N], A row-major, B given transposed (Bt[N,K] row-major).
// Block tile 128x128, 4 waves (2x2), per-wave 64x64 via 2x2 MFMA 32x32x16 bf16.
// Primary path: all-bf16 operands, global_load_lds staging, 3-buffer depth-2
// pipeline with counted vmcnt(4) (loads stay in flight across barriers).
// LDS tile [128 rows][4 slots x 8 bf16]; slot swizzled: LDS[r][s] holds global
// slot s ^ ((r>>1)&3)  — applied on the (per-lane) global source address
// (global_load_lds writes linearly) and on the ds_read side. Cuts the 16-way
// fragment-read bank conflict to 4-way.
__global__ __launch_bounds__(256) void gemm_stage(GBatch gb) {
  __shared__ __align__(16) char smem[49152];
  bf16_t* const sAb = (bf16_t*)smem;             // 3 bufs x 4096 elems
  bf16_t* const sBb = (bf16_t*)smem + 3 * 4096;  // 3 bufs x 4096 elems
  float* const sT = (float*)smem;                // epilogue reuse (17KB < 48KB)

  const int bid = blockIdx.x;
  int di = 0;
#pragma unroll 1
  for (int i = 1; i < gb.nd; ++i)
    if (bid >= gb.d[i].bstart) di = i;
  const GDesc g = gb.d[di];

  const unsigned fl = *gb.flagp;
  bool a32 = false, b32 = false;
  const bf16_t* Ab; const bf16_t* Bb;
  const float* Af = (const float*)g.A;
  const float* Bf = (const float*)g.Bt;
  if (fl != 0) {
    Ab = (const bf16_t*)g.A; Bb = (const bf16_t*)g.Bt;
  } else {
    if (g.aext) { Ab = (const bf16_t*)g.Ac; a32 = (g.Ac == nullptr); }
    else Ab = (const bf16_t*)g.A;
    if (g.bext) { Bb = (const bf16_t*)g.Bc; b32 = (g.Bc == nullptr); }
    else Bb = (const bf16_t*)g.Bt;
  }

  const int t = threadIdx.x;
  const int w = t >> 6, lane = t & 63;
  const int local = bid - g.bstart;
  const int bm = local % g.nbm, bn = local / g.nbm;
  const int m0 = bm * 128, c0 = bn * 128;

  // staging: thread t -> LDS (row = t>>2, slot = t&3); global slot = (t&3)^f(row),
  // f(row) = (row>>1)&3 = (t>>3)&3. Same f for row and row+64.
  const int srow = t >> 2;
  const int sc = ((t & 3) ^ ((t >> 3) & 3)) * 8;
  const u64 eA0 = (u64)imin(m0 + srow, g.M - 1) * g.lda + sc;
  const u64 eA1 = (u64)imin(m0 + 64 + srow, g.M - 1) * g.lda + sc;
  const u64 eB0 = (u64)imin(c0 + srow, g.N - 1) * g.ldbt + sc;
  const u64 eB1 = (u64)imin(c0 + 64 + srow, g.N - 1) * g.ldbt + sc;

  const int wm = w & 1, wn = w >> 1;
  const int lrow = lane & 31, lhalf = lane >> 5;
  const int fr = (lrow >> 1) & 3;                 // read-side swizzle field
  const int aoffb = (wm * 64 + lrow) * 32;
  const int boffb = (wn * 64 + lrow) * 32;

  f32x16 acc[2][2] = {};

  auto cvt8 = [](const float* p) {
    float4 u0 = *(const float4*)p, u1 = *(const float4*)(p + 4);
    bf16x8 r;
    r[0] = (bf16_t)u0.x; r[1] = (bf16_t)u0.y; r[2] = (bf16_t)u0.z; r[3] = (bf16_t)u0.w;
    r[4] = (bf16_t)u1.x; r[5] = (bf16_t)u1.y; r[6] = (bf16_t)u1.z; r[7] = (bf16_t)u1.w;
    return r;
  };

  auto mfma_step = [&](const bf16_t* bA, const bf16_t* bB) {
    bf16x8 af[2][2], bb[2][2];
#pragma unroll
    for (int s = 0; s < 2; ++s)
#pragma unroll
      for (int h = 0; h < 2; ++h) {
        const int sl = ((lhalf + 2 * h) ^ fr) * 8;
        af[s][h] = *(const bf16x8*)&bA[aoffb + s * 1024 + sl];
        bb[s][h] = *(const bf16x8*)&bB[boffb + s * 1024 + sl];
      }
#pragma unroll
    for (int h = 0; h < 2; ++h)
#pragma unroll
      for (int sm = 0; sm < 2; ++sm)
#pragma unroll
        for (int sn = 0; sn < 2; ++sn)
          acc[sm][sn] = __builtin_amdgcn_mfma_f32_32x32x16_bf16(
              af[sm][h], bb[sn][h], acc[sm][sn], 0, 0, 0);
  };

  auto issueP = [&](int kk, int buf) {
    const u64 kb = (u64)kk * 32;
    bf16_t* dA = sAb + buf * 4096 + w * 512;
    bf16_t* dB = sBb + buf * 4096 + w * 512;
    GLD16(Ab + eA0 + kb, dA);
    GLD16(Ab + eA1 + kb, dA + 2048);
    GLD16(Bb + eB0 + kb, dB);
    GLD16(Bb + eB1 + kb, dB + 2048);
  };

  const int kfull = g.K >> 5;
  if (!a32 && !b32) {
    // ---- depth-2 pipelined, counted vmcnt
    issueP(0, 0);
    if (kfull > 1) {
      issueP(1, 1);
      asm volatile("s_waitcnt vmcnt(4)" ::: "memory");
    } else {
      asm volatile("s_waitcnt vmcnt(0)" ::: "memory");
    }
    __builtin_amdgcn_s_barrier();
    int cur = 0, nxt = 2;
#pragma unroll 1
    for (int kk = 0; kk < kfull; ++kk) {
      const bool pre = (kk + 2 < kfull);
      if (pre) issueP(kk + 2, nxt);
      mfma_step(sAb + cur * 4096, sBb + cur * 4096);
      if (pre) asm volatile("s_waitcnt vmcnt(4)" ::: "memory");
      else     asm volatile("s_waitcnt vmcnt(0)" ::: "memory");
      __builtin_amdgcn_s_barrier();
      cur = (cur == 2) ? 0 : cur + 1;
      nxt = (nxt == 2) ? 0 : nxt + 1;
    }
  } else {
    // ---- legacy synchronous single-buffer loop (only if workspace too small)
#pragma unroll 1
    for (int kk = 0; kk < kfull; ++kk) {
      const u64 kb = (u64)kk * 32;
      if (!a32) {
        GLD16(Ab + eA0 + kb, sAb + w * 512);
        GLD16(Ab + eA1 + kb, sAb + w * 512 + 2048);
      } else {
        *(bf16x8*)(sAb + (u64)t * 8) = cvt8(Af + eA0 + kb);
        *(bf16x8*)(sAb + (u64)t * 8 + 2048) = cvt8(Af + eA1 + kb);
      }
      if (!b32) {
        GLD16(Bb + eB0 + kb, sBb + w * 512);
        GLD16(Bb + eB1 + kb, sBb + w * 512 + 2048);
      } else {
        *(bf16x8*)(sBb + (u64)t * 8) = cvt8(Bf + eB0 + kb);
        *(bf16x8*)(sBb + (u64)t * 8 + 2048) = cvt8(Bf + eB1 + kb);
      }
      __syncthreads();
      mfma_step(sAb, sBb);
      __syncthreads();
    }
  }

  if (g.K & 16) {  // K tail of 16 (K = 2000, 6000): stage 16 cols, zero the rest
    const u64 k0 = (u64)(g.K & ~31);
    const int row = t >> 1;
    const int g0 = t & 1;                   // global slot holding data
    const int ftl = (row >> 1) & 3;         // swizzle field for this row
    const u64 ea = (u64)imin(m0 + row, g.M - 1) * g.lda + k0 + g0 * 8;
    const u64 eb = (u64)imin(c0 + row, g.N - 1) * g.ldbt + k0 + g0 * 8;
    bf16x8 va, vb;
    if (!a32) va = *(const bf16x8*)(Ab + ea);
    else va = cvt8(Af + ea);
    if (!b32) vb = *(const bf16x8*)(Bb + eb);
    else vb = cvt8(Bf + eb);
    uint4 z = {0, 0, 0, 0};
    *(bf16x8*)&sAb[row * 32 + ((g0 ^ ftl) * 8)] = va;
    *(uint4*)&sAb[row * 32 + (((g0 | 2) ^ ftl) * 8)] = z;
    *(bf16x8*)&sBb[row * 32 + ((g0 ^ ftl) * 8)] = vb;
    *(uint4*)&sBb[row * 32 + (((g0 | 2) ^ ftl) * 8)] = z;
    __syncthreads();
    mfma_step(sAb, sBb);
    __syncthreads();
  }

  // C/D layout (m74/m101): col = lane&31, row = (reg&3) + 8*(reg>>2) + 4*(lane>>5)
  if (g.bias) {  // bias arrays are always external
#pragma unroll
    for (int sm = 0; sm < 2; ++sm)
#pragma unroll
      for (int reg = 0; reg < 16; ++reg) {
        int mg = imin(m0 + wm * 64 + sm * 32 + (reg & 3) + 8 * (reg >> 2) + 4 * lhalf,
                      g.M - 1);
        float bv = (fl == 0) ? ((const float*)g.bias)[mg]
                             : (float)((const bf16_t*)g.bias)[mg];
        acc[sm][0][reg] += bv;
        acc[sm][1][reg] += bv;
      }
  }
  if (g.outN) {
#pragma unroll
    for (int sm = 0; sm < 2; ++sm)
#pragma unroll
      for (int sn = 0; sn < 2; ++sn) {
        int cg = c0 + wn * 64 + sn * 32 + lrow;
        if (cg < g.N) {
#pragma unroll
          for (int reg = 0; reg < 16; ++reg) {
            int mg = m0 + wm * 64 + sm * 32 + (reg & 3) + 8 * (reg >> 2) + 4 * lhalf;
            if (mg < g.M) g.outN[(u64)mg * g.ldN + cg] = (bf16_t)acc[sm][sn][reg];
          }
        }
      }
  }
  if (g.outT) {  // transpose 32-col chunks through LDS, coalesced bf16x4 stores
#pragma unroll
    for (int cc = 0; cc < 4; ++cc) {
      __syncthreads();
      if (wn == (cc >> 1)) {
        const int sn = cc & 1;
#pragma unroll
        for (int sm = 0; sm < 2; ++sm)
#pragma unroll
          for (int rq = 0; rq < 4; ++rq) {
            f32x4v v;
            v.x = acc[sm][sn][rq * 4 + 0];
            v.y = acc[sm][sn][rq * 4 + 1];
            v.z = acc[sm][sn][rq * 4 + 2];
            v.w = acc[sm][sn][rq * 4 + 3];
            int ml = wm * 64 + sm * 32 + 8 * rq + 4 * lhalf;
            *(f32x4v*)&sT[lrow * 132 + ml] = v;
          }
      }
      __syncthreads();
#pragma unroll
      for (int p = 0; p < 4; ++p) {
        int c = (t >> 5) + p * 8, mq = t & 31;
        f32x4v v = *(const f32x4v*)&sT[c * 132 + mq * 4];
        int cg = c0 + cc * 32 + c;
        if (cg < g.N) {
          union { bf16_t b[4]; uint2 u; } cv;
          cv.b[0] = (bf16_t)v.x; cv.b[1] = (bf16_t)v.y;
          cv.b[2] = (bf16_t)v.z; cv.b[3] = (bf16_t)v.w;
          *(uint2*)(g.outT + (u64)cg * g.ldT + m0 + mq * 4) = cv.u;
        }
      }
    }
  }
}

// out[j][i] = (bf16)in[i][j]; 64x64 tiles; dual-dtype input read.
// Optionally also emits a row-major bf16 copy (out_rm) when input is f32.
__global__ __launch_bounds__(256) void transpose_any(const void* in, bf16_t* out,
                                                     bf16_t* out_rm,
                                                     int Ri, int Ci, int tilesC,
                                                     const unsigned* flagp) {
  __shared__ bf16_t tile[64 * 65];
  const bool f32m = (*flagp == 0);
  const int bi = blockIdx.x / tilesC, bj = blockIdx.x % tilesC;
  const int i0 = bi * 64, j0 = bj * 64;
  const int t = threadIdx.x;
#pragma unroll
  for (int it = 0; it < 16; ++it) {
    int flidx = t + it * 256;
    int r = flidx >> 6, c = flidx & 63;
    int gi = i0 + r, gj = j0 + c;
    bf16_t v = (bf16_t)0.f;
    if (gi < Ri && gj < Ci) {
      u64 idx = (u64)gi * Ci + gj;
      v = f32m ? (bf16_t)((const float*)in)[idx] : ((const bf16_t*)in)[idx];
      if (out_rm && f32m) out_rm[idx] = v;
    }
    tile[r * 65 + c] = v;
  }
  __syncthreads();
#pragma unroll
  for (int it = 0; it < 2; ++it) {
    int flidx = t + it * 256;
    int c = flidx >> 3, rb = (flidx & 7) * 8;
    int gj = j0 + c;
    if (gj < Ci && (i0 + rb) < Ri) {
      union { bf16_t b[8]; uint4 u; } cv;
#pragma unroll
      for (int k2 = 0; k2 < 8; ++k2) cv.b[k2] = tile[(rb + k2) * 65 + c];
      *(uint4*)(out + (u64)gj * Ri + i0 + rb) = cv.u;
    }
  }
}

// Wp[o][k*128+i] = w[i][o][k]  (w: [128,128,ks] row-major), dual-dtype read
struct RPack {
  const void* src[3]; bf16_t* dst[3];
  int R[3], ks[3], base[3], total;
  const unsigned* flagp;
};
__global__ __launch_bounds__(256) void repack_w(RPack rp) {
  int id = blockIdx.x * 256 + threadIdx.x;
  if (id >= rp.total) return;
  const bool f32m = (*rp.flagp == 0);
  int si = 0;
  if (id >= rp.base[1]) si = 1;
  if (id >= rp.base[2]) si = 2;
  int e = id - rp.base[si];
  int R = rp.R[si], ks = rp.ks[si];
  int o = e / R, col = e - o * R;
  int k = col >> 7, i = col & 127;
  u64 sidx = ((u64)i * 128 + o) * ks + k;
  rp.dst[si][e] = f32m ? (bf16_t)((const float*)rp.src[si])[sidx]
                       : ((const bf16_t*)rp.src[si])[sidx];
}

__global__ __launch_bounds__(256) void final_head(const bf16_t* h0t, const void* ow,
                                                  const void* ob, void* out,
                                                  const unsigned* flagp) {
  int n = blockIdx.x * 256 + threadIdx.x;
  if (n >= 2000) return;
  const bool f32m = (*flagp == 0);
  float a0 = f32m ? ((const float*)ob)[0] : (float)((const bf16_t*)ob)[0];
  float a1 = f32m ? ((const float*)ob)[1] : (float)((const bf16_t*)ob)[1];
#pragma unroll 4
  for (int i = 0; i < 128; ++i) {
    float hv = (float)h0t[i * 2048 + n];
    float w0 = f32m ? ((const float*)ow)[i] : (float)((const bf16_t*)ow)[i];
    float w1 = f32m ? ((const float*)ow)[128 + i] : (float)((const bf16_t*)ow)[128 + i];
    a0 += hv * w0;
    a1 += hv * w1;
  }
  float s0 = 1.f / (1.f + __expf(-a0));
  float s1 = 1.f / (1.f + __expf(-a1));
  if (f32m) {
    ((float*)out)[n * 2 + 0] = s0;
    ((float*)out)[n * 2 + 1] = s1;
  } else {
    ((bf16_t*)out)[n * 2 + 0] = (bf16_t)s0;
    ((bf16_t*)out)[n * 2 + 1] = (bf16_t)s1;
  }
}

extern "C" void kernel_launch(void* const* d_in, const int* in_sizes, int n_in,
                              void* d_out, int out_size, void* d_ws, size_t ws_size,
                              hipStream_t stream) {
  const void *x0 = d_in[0], *x1 = d_in[1], *x2 = d_in[2];
  const void *L0 = d_in[3], *L1d = d_in[4], *L1u = d_in[5];
  const void *B1m = d_in[8];
  const void *B2m = d_in[9];
  const void *inw0 = d_in[10], *inb0 = d_in[11], *inw1 = d_in[12], *inb1 = d_in[13],
             *inw2 = d_in[14], *inb2 = d_in[15];
  const void *w0a = d_in[16], *w1a = d_in[17], *w0b = d_in[19];
  const void *outw = d_in[22], *outb = d_in[23];
  // dead inputs: L2d(6), L2u(7), l0_w2(18), l1_w1(20), l1_w2(21) — face space
  // never reaches the node logits.

  char* wsb = (char*)d_ws;
  size_t off = 0;
  auto alloc = [&](size_t elems) {
    bf16_t* p = (bf16_t*)(wsb + off);
    off = (off + elems * 2 + 255) & ~(size_t)255;
    return p;
  };
  unsigned* flagp = (unsigned*)alloc(128);
  bf16_t* B1t = alloc((size_t)6000 * 2000);   // B1^T
  bf16_t* h0t = alloc(128 * 2048);            // channel-major features [128, n_pad]
  bf16_t* h1t = alloc(128 * 6016);
  bf16_t* h2t = alloc(128 * 4096);
  bf16_t* p_t = alloc(128 * 2048);
  bf16_t* q_t = alloc(128 * 6016);
  bf16_t* r_t = alloc(128 * 6016);
  bf16_t* a_t = alloc(128 * 2048);
  bf16_t* c_t = alloc(128 * 2048);
  bf16_t* e_t = alloc(128 * 6016);
  bf16_t* g_t = alloc(128 * 6016);
  bf16_t* j_t = alloc(128 * 6016);
  bf16_t* l_t = alloc(128 * 6016);
  bf16_t* sA0 = alloc((size_t)2000 * 768);    // layer-1 x0 slice stack [n, 6*128]
  bf16_t* sA1 = alloc((size_t)6000 * 1408);   // layer-1 x1 slice stack [n, 11*128]
  bf16_t* sB0 = alloc((size_t)2000 * 768);    // layer-2 x0 slice stack
  bf16_t* Wp0a = alloc(768 * 128);
  bf16_t* Wp1a = alloc(1408 * 128);
  bf16_t* Wp0b = alloc(768 * 128);
  // bf16 conversion twins for external operands (used when inputs are f32)
  bf16_t* L0c  = alloc((size_t)2000 * 2000);
  bf16_t* L1dc = alloc((size_t)6000 * 6000);
  bf16_t* L1uc = alloc((size_t)6000 * 6000);
  bf16_t* B2c  = alloc((size_t)6000 * 4000);
  bf16_t* B1rm = alloc((size_t)2000 * 6000);  // row-major bf16 B1 (via transpose pass)
  bf16_t* x0c  = alloc((size_t)2000 * 128);
  bf16_t* x1c  = alloc((size_t)6000 * 128);
  bf16_t* x2c  = alloc((size_t)4000 * 128);
  bf16_t* iw0c = alloc(128 * 128);
  bf16_t* iw1c = alloc(128 * 128);
  bf16_t* iw2c = alloc(128 * 128);

  const bool fit = off <= ws_size;
  auto C = [&](bf16_t* p) { return fit ? p : (bf16_t*)nullptr; };

  // 0) dtype probe (on L0)
  detect_dtype<<<1, 256, 0, stream>>>(L0, flagp);

  // 0b) f32 -> bf16 conversion pre-pass (streaming, full-BW; no-op if bf16)
  if (fit) {
    CvtBatch cb{};
    cb.flagp = flagp;
    int nj = 0; unsigned tot4 = 0;
    auto addcvt = [&](const void* src, bf16_t* dst, size_t n) {
      cb.j[nj].src = (const float*)src; cb.j[nj].dst = dst;
      cb.base[nj] = tot4; tot4 += (unsigned)(n >> 2); nj++;
    };
    addcvt(L0, L0c, (size_t)2000 * 2000);
    addcvt(L1d, L1dc, (size_t)6000 * 6000);
    addcvt(L1u, L1uc, (size_t)6000 * 6000);
    addcvt(B2m, B2c, (size_t)6000 * 4000);
    addcvt(x0, x0c, (size_t)2000 * 128);
    addcvt(x1, x1c, (size_t)6000 * 128);
    addcvt(x2, x2c, (size_t)4000 * 128);
    addcvt(inw0, iw0c, 128 * 128);
    addcvt(inw1, iw1c, 128 * 128);
    addcvt(inw2, iw2c, 128 * 128);
    cb.nj = nj; cb.total4 = tot4;
    cvt_f32_bf16<<<2048, 256, 0, stream>>>(cb);
  }

  // 1) repack einsum weights (only the alive ones)
  RPack rp{};
  rp.src[0] = w0a; rp.dst[0] = Wp0a; rp.R[0] = 768;  rp.ks[0] = 6;  rp.base[0] = 0;
  rp.src[1] = w1a; rp.dst[1] = Wp1a; rp.R[1] = 1408; rp.ks[1] = 11; rp.base[1] = 98304;
  rp.src[2] = w0b; rp.dst[2] = Wp0b; rp.R[2] = 768;  rp.ks[2] = 6;  rp.base[2] = 98304 + 180224;
  rp.total = 98304 + 180224 + 98304;
  rp.flagp = flagp;
  repack_w<<<(rp.total + 255) / 256, 256, 0, stream>>>(rp);

  // 2) B1^T (+ row-major bf16 copy of B1 when f32)
  transpose_any<<<32 * 94, 256, 0, stream>>>(B1m, B1t, C(B1rm), 2000, 6000, 94, flagp);

  GBatch gb; int tot;
  gb.flagp = flagp;
  auto reset = [&] { gb.nd = 0; tot = 0; };
  auto add = [&](const void* A, const void* Ac, int aext,
                 const void* Bt, const void* Bc, int bext, const void* bias,
                 bf16_t* outN, int ldN, bf16_t* outT, int ldT,
                 int M, int N, int K, int lda, int ldbt) {
    GDesc& d = gb.d[gb.nd++];
    d.A = A; d.Ac = Ac; d.Bt = Bt; d.Bc = Bc; d.bias = bias;
    d.outN = outN; d.outT = outT;
    d.M = M; d.N = N; d.K = K; d.lda = lda; d.ldbt = ldbt; d.ldN = ldN; d.ldT = ldT;
    d.aext = aext; d.bext = bext;
    d.bstart = tot; d.nbm = (M + 127) >> 7;
    tot += d.nbm * ((N + 127) >> 7);
  };
  auto fire = [&] { gemm_stage<<<tot, 256, 0, stream>>>(gb); };

  // input linears: h^T = W x^T (+b). M=128(ch), N=n, K=128.
  reset();
  add(inw0, C(iw0c), 1, x0, C(x0c), 1, inb0, h0t, 2048, sA0, 768, 128, 2000, 128, 128, 128);
  add(inw1, C(iw1c), 1, x1, C(x1c), 1, inb1, h1t, 6016, sA1, 1408, 128, 6000, 128, 128, 128);
  add(inw2, C(iw2c), 1, x2, C(x2c), 1, inb2, h2t, 4096, nullptr, 0, 128, 4000, 128, 128, 128);
  fire();

  // layer 1, stage A: projections + first cheb steps on h
  reset();
  add(B1m, C(B1rm), 1, h1t, nullptr, 0, nullptr, sA0 + 3 * 128, 768, p_t, 2048, 2000, 128, 6000, 6000, 6016);  // p
  add(B1t, nullptr, 0, h0t, nullptr, 0, nullptr, sA1 + 5 * 128, 1408, q_t, 6016, 6000, 128, 2000, 2000, 2048); // q
  add(B2m, C(B2c), 1, h2t, nullptr, 0, nullptr, sA1 + 8 * 128, 1408, r_t, 6016, 6000, 128, 4000, 4000, 4096);  // r
  add(L0, C(L0c), 1, h0t, nullptr, 0, nullptr, sA0 + 1 * 128, 768, a_t, 2048, 2000, 128, 2000, 2000, 2048);    // a
  add(L1d, C(L1dc), 1, h1t, nullptr, 0, nullptr, sA1 + 1 * 128, 1408, e_t, 6016, 6000, 128, 6000, 6000, 6016); // e
  add(L1u, C(L1uc), 1, h1t, nullptr, 0, nullptr, sA1 + 3 * 128, 1408, g_t, 6016, 6000, 128, 6000, 6000, 6016); // g
  fire();

  // layer 1, stage B
  reset();
  add(L0, C(L0c), 1, p_t, nullptr, 0, nullptr, sA0 + 4 * 128, 768, c_t, 2048, 2000, 128, 2000, 2000, 2048);    // c
  add(L0, C(L0c), 1, a_t, nullptr, 0, nullptr, sA0 + 2 * 128, 768, nullptr, 0, 2000, 128, 2000, 2000, 2048);   // b
  add(L1d, C(L1dc), 1, q_t, nullptr, 0, nullptr, sA1 + 6 * 128, 1408, j_t, 6016, 6000, 128, 6000, 6000, 6016); // j
  add(L1d, C(L1dc), 1, e_t, nullptr, 0, nullptr, sA1 + 2 * 128, 1408, nullptr, 0, 6000, 128, 6000, 6000, 6016);// f
  add(L1u, C(L1uc), 1, r_t, nullptr, 0, nullptr, sA1 + 9 * 128, 1408, l_t, 6016, 6000, 128, 6000, 6000, 6016); // l
  add(L1u, C(L1uc), 1, g_t, nullptr, 0, nullptr, sA1 + 4 * 128, 1408, nullptr, 0, 6000, 128, 6000, 6000, 6016);// i
  fire();

  // layer 1, stage C
  reset();
  add(L0, C(L0c), 1, c_t, nullptr, 0, nullptr, sA0 + 5 * 128, 768, nullptr, 0, 2000, 128, 2000, 2000, 2048);   // d
  add(L1d, C(L1dc), 1, j_t, nullptr, 0, nullptr, sA1 + 7 * 128, 1408, nullptr, 0, 6000, 128, 6000, 6000, 6016);// k
  add(L1u, C(L1uc), 1, l_t, nullptr, 0, nullptr, sA1 + 10 * 128, 1408, nullptr, 0, 6000, 128, 6000, 6000, 6016);// m
  fire();

  // layer 1, stage D: einsums (y2 dead)
  reset();
  add(sA0, nullptr, 0, Wp0a, nullptr, 0, nullptr, sB0, 768, h0t, 2048, 2000, 128, 768, 768, 768);     // y0 -> h0'
  add(sA1, nullptr, 0, Wp1a, nullptr, 0, nullptr, nullptr, 0, h1t, 6016, 6000, 128, 1408, 1408, 1408);// y1 -> h1'
  fire();

  // layer 2 (only the node-space path survives)
  reset();
  add(B1m, C(B1rm), 1, h1t, nullptr, 0, nullptr, sB0 + 3 * 128, 768, p_t, 2048, 2000, 128, 6000, 6000, 6016);  // p2
  add(L0, C(L0c), 1, h0t, nullptr, 0, nullptr, sB0 + 1 * 128, 768, a_t, 2048, 2000, 128, 2000, 2000, 2048);    // a2
  fire();
  reset();
  add(L0, C(L0c), 1, p_t, nullptr, 0, nullptr, sB0 + 4 * 128, 768, c_t, 2048, 2000, 128, 2000, 2000, 2048);    // c2
  add(L0, C(L0c), 1, a_t, nullptr, 0, nullptr, sB0 + 2 * 128, 768, nullptr, 0, 2000, 128, 2000, 2000, 2048);   // b2
  fire();
  reset();
  add(L0, C(L0c), 1, c_t, nullptr, 0, nullptr, sB0 + 5 * 128, 768, nullptr, 0, 2000, 128, 2000, 2000, 2048);   // d2
  fire();
  reset();
  add(sB0, nullptr, 0, Wp0b, nullptr, 0, nullptr, nullptr, 0, h0t, 2048, 2000, 128, 768, 768, 768);            // y0' -> h0''
  fire();

  // head: logits + sigmoid
  final_head<<<8, 256, 0, stream>>>(h0t, outw, outb, d_out, flagp);
}